// Round 6
// baseline (127.475 us; speedup 1.0000x reference)
//
#include <hip/hip_runtime.h>
#include <stdint.h>

#define NPTS   65536
#define DDIM   128
#define KCODES 1024

typedef __attribute__((ext_vector_type(8))) _Float16  half8;
typedef __attribute__((ext_vector_type(4))) float     f32x4;
typedef __attribute__((ext_vector_type(4))) int       int4v;
typedef __attribute__((ext_vector_type(2))) _Float16  half2v;

// ---------------- numeric helpers (LOCKED — absmax=0 rounds 2,3,4,5) ----------------
// 2-limb fp16 Dekker split: x ~= (float)hi + (float)lo / 2048.
__device__ __forceinline__ void split16(float x, _Float16& hi, _Float16& lo) {
  _Float16 h = (__builtin_fabsf(x) < 6.103515625e-05f) ? (_Float16)0.f : (_Float16)x;
  hi = h;
  lo = (_Float16)(__fmul_rn(__fsub_rn(x, (float)h), 2048.f));
}

// numpy pairwise sum of squares for n=128 (bit-exact np.sum(x*x,-1)); serial form.
__device__ __forceinline__ float np_sumsq_128(const float* __restrict__ row) {
  float r[8];
#pragma unroll
  for (int k = 0; k < 8; ++k) r[k] = __fmul_rn(row[k], row[k]);
  for (int i = 8; i < 128; i += 8)
#pragma unroll
    for (int k = 0; k < 8; ++k) r[k] = __fadd_rn(r[k], __fmul_rn(row[i + k], row[i + k]));
  float s01 = __fadd_rn(r[0], r[1]), s23 = __fadd_rn(r[2], r[3]);
  float s45 = __fadd_rn(r[4], r[5]), s67 = __fadd_rn(r[6], r[7]);
  return __fadd_rn(__fadd_rn(s01, s23), __fadd_rn(s45, s67));
}

// global->LDS async copy, 16B/lane. LDS dest = wave-uniform base + lane*16.
__device__ __forceinline__ void async_copy16(const void* g, void* l) {
  auto gp = (const __attribute__((address_space(1))) unsigned int*)(uintptr_t)g;
  auto lp = (__attribute__((address_space(3))) unsigned int*)(unsigned)(uintptr_t)l;
  __builtin_amdgcn_global_load_lds(gp, lp, 16, 0, 0);
}

// ---------------- workspace layout ----------------
constexpr size_t SZ_B   = (size_t)KCODES * DDIM * 2;  // 256 KB per B limb
constexpr size_t OFF_B1 = 0;
constexpr size_t OFF_B2 = SZ_B;
constexpr size_t OFF_C2 = 2 * SZ_B;
constexpr size_t WS_NEED = OFF_C2 + (size_t)KCODES * 4;  // ~516 KB

// ---------------- prep: codebook limbs (XOR-swizzled k-groups) + c2 ----------------
// Element (code,k), kg=k/8, stored at row offset (kg ^ (code&15))*8 + k%8 so that
// linear LDS staging + ds_read_b128 fragment reads are bank-uniform (0 conflicts,
// verified rounds 3-5). c2 via the 8-lane shuffle tree (bit-exact, verified).
__global__ __launch_bounds__(256) void vq_prep_cb(const float* __restrict__ cb,
                                                  _Float16* __restrict__ B1,
                                                  _Float16* __restrict__ B2,
                                                  float* __restrict__ c2) {
  const int w = threadIdx.x >> 6, ln = threadIdx.x & 63;
  const int code = blockIdx.x * 4 + w;  // one wave per code row
  const float2 cv = ((const float2*)(cb + (size_t)code * DDIM))[ln];
  _Float16 h0, l0, h1, l1;
  split16(cv.x, h0, l0); split16(cv.y, h1, l1);
  const int kg = ln >> 2;
  const int o  = 2 * (ln & 3);
  const size_t dst = (size_t)code * DDIM + (size_t)((kg ^ (code & 15)) * 8 + o);
  *(half2v*)(B1 + dst) = (half2v){h0, h1};
  *(half2v*)(B2 + dst) = (half2v){l0, l1};

  if (threadIdx.x < 32) {  // 8 lanes per code, 4 codes
    const int cc = blockIdx.x * 4 + (threadIdx.x >> 3), jj = threadIdx.x & 7;
    const float* row = cb + (size_t)cc * DDIM;
    float e = row[jj];
    float acc = __fmul_rn(e, e);
    for (int i = 1; i < 16; ++i) {
      e = row[i * 8 + jj];
      acc = __fadd_rn(acc, __fmul_rn(e, e));
    }
    float a1 = __fadd_rn(acc, __shfl_xor(acc, 1));
    float a2 = __fadd_rn(a1, __shfl_xor(a1, 2));
    float a4 = __fadd_rn(a2, __shfl_xor(a2, 4));
    if (jj == 0) c2[cc] = a4;
  }
}

// ---------------- main fused z2 + GEMM + argmin ----------------
// grid 512, block 256 = 4 waves stacked by rows: wave tile 32 rows x 64 codes.
// Round-6 changes vs round 5 (arithmetic per element bit-identical):
//  - b1 fragments held in regs across pass1->pass2 (LDS reads 48->32 per iter)
//  - acc double-buffered (unroll-2 parity): epilogue(iter-1) issued right after
//    pass0(iter) MFMAs -> VALU overlaps the MFMA drain
//  - fma(-2,dot,z2) == fsub(z2, fmul(2,dot)) exactly (2*dot exact)
//  - phase-0 z2 double-buffered (LsA/LsB), c2 staged async during phase 0
__global__ __launch_bounds__(256, 2) void vq_gemm(
    const float* __restrict__ z,
    const unsigned short* __restrict__ B1g, const unsigned short* __restrict__ B2g,
    const float* __restrict__ c2g, int* __restrict__ out) {
  __shared__ alignas(16) char smem[33792 + 4096 + 512];  // 38400 B
  unsigned short* Bs1 = (unsigned short*)smem;
  unsigned short* Bs2 = (unsigned short*)(smem + 16384);
  float* c2sh = (float*)(smem + 33792);
  float* z2sh = (float*)(smem + 33792 + 4096);
  float* LsA  = (float*)smem;            // 32x132 fp32, phase 0 only
  float* LsB  = (float*)(smem + 16896);  // second buffer, phase 0 only

  const int tid = threadIdx.x;
  const int ln = tid & 63, wr = tid >> 6;
  const int l15 = ln & 15, q = ln >> 4;
  const size_t row0 = (size_t)blockIdx.x * 128;
  const float4* z4 = (const float4*)z;

  // c2 -> LDS (c2sh disjoint from Ls buffers; drains at any later barrier)
  async_copy16(c2g + tid * 4, c2sh + tid * 4);

  // ---- phase 0: z2 for own 128 rows (np-exact tree; LsA/LsB double-buffer) ----
  auto stagez = [&](int cc, float* Ls) {
#pragma unroll
    for (int j = 0; j < 4; ++j) {
      const int idx = tid + j * 256;  // < 1024 float4 = 32 rows
      float4 v = z4[(row0 + cc * 32) * 32 + idx];
      *(float4*)&Ls[(idx >> 5) * 132 + (idx & 31) * 4] = v;
    }
  };
  stagez(0, LsA);
  for (int cc = 0; cc < 4; ++cc) {
    __syncthreads();
    if (cc < 3) stagez(cc + 1, (cc & 1) ? LsA : LsB);
    const float* Ls = (cc & 1) ? LsB : LsA;
    const int r = tid >> 3, jj = tid & 7;
    const float* row = &Ls[r * 132];
    float e = row[jj];
    float acc = __fmul_rn(e, e);
    for (int i = 1; i < 16; ++i) {
      e = row[i * 8 + jj];
      acc = __fadd_rn(acc, __fmul_rn(e, e));
    }
    float a1 = __fadd_rn(acc, __shfl_xor(acc, 1));
    float a2 = __fadd_rn(a1, __shfl_xor(a1, 2));
    float a4 = __fadd_rn(a2, __shfl_xor(a2, 4));
    if (jj == 0) z2sh[cc * 32 + r] = a4;
  }
  __syncthreads();  // phase-0 reads done; Ls region may now become B tiles

  // ---- stage B tile 0 (both limbs); A-frag loads (L2-warm) overlap the drain ----
#pragma unroll
  for (int j = 0; j < 4; ++j) {
    const int s = tid + j * 256;
    async_copy16(B2g + s * 8, Bs2 + s * 8);
    async_copy16(B1g + s * 8, Bs1 + s * 8);
  }

  half8 a1f[2][4], a2f[2][4];
#pragma unroll
  for (int rf = 0; rf < 2; ++rf) {
    const float* zr = z + (row0 + wr * 32 + rf * 16 + l15) * DDIM;
#pragma unroll
    for (int ks = 0; ks < 4; ++ks) {
      float tmp[8];
      *(float4*)tmp       = *(const float4*)(zr + ks * 32 + q * 8);
      *(float4*)(tmp + 4) = *(const float4*)(zr + ks * 32 + q * 8 + 4);
      half8 h, l;
#pragma unroll
      for (int e = 0; e < 8; ++e) {
        _Float16 hh, ll;
        split16(tmp[e], hh, ll);
        h[e] = hh; l[e] = ll;
      }
      a1f[rf][ks] = h; a2f[rf][ks] = l;
    }
  }

  float mv[8];
  int mi[8];
#pragma unroll
  for (int i = 0; i < 8; ++i) { mv[i] = 3.0e38f; mi[i] = 0; }

  __syncthreads();  // drain B tile 0 + c2 staging

  float z2r[8];
#pragma unroll
  for (int rf = 0; rf < 2; ++rf)
#pragma unroll
    for (int reg = 0; reg < 4; ++reg)
      z2r[rf * 4 + reg] = z2sh[wr * 32 + rf * 16 + q * 4 + reg];

  // epilogue: np-exact fp32 distance fold (fma exact-equiv, LOCKED order)
  auto epilogue = [&](f32x4 (&a)[2][4], int c0p) {
    float c2v[4];
#pragma unroll
    for (int cf = 0; cf < 4; ++cf) c2v[cf] = c2sh[c0p + cf * 16 + l15];
#pragma unroll
    for (int rf = 0; rf < 2; ++rf)
#pragma unroll
      for (int reg = 0; reg < 4; ++reg) {
        const int slot = rf * 4 + reg;
#pragma unroll
        for (int cf = 0; cf < 4; ++cf) {
          float v = __fadd_rn(__builtin_fmaf(-2.f, a[rf][cf][reg], z2r[slot]), c2v[cf]);
          int idx = c0p + cf * 16 + l15;
          if (v < mv[slot]) { mv[slot] = v; mi[slot] = idx; }
        }
      }
  };

  f32x4 acc[2][2][4];  // parity-double-buffered accumulators

#pragma unroll 2
  for (int it = 0; it < 16; ++it) {
    const int p = it & 1;
    const int c0 = it * 64;
#pragma unroll
    for (int rf = 0; rf < 2; ++rf)
#pragma unroll
      for (int cf = 0; cf < 4; ++cf) acc[p][rf][cf] = (f32x4){0.f, 0.f, 0.f, 0.f};

    // ---- pass 0: a1 * b2 (reads Bs2 only) ----
#pragma unroll
    for (int ks = 0; ks < 4; ++ks) {
      half8 b[4];
#pragma unroll
      for (int cf = 0; cf < 4; ++cf)
        b[cf] = *(const half8*)&Bs2[(cf * 16 + l15) * 128 + (((ks * 4 + q) ^ l15) * 8)];
#pragma unroll
      for (int rf = 0; rf < 2; ++rf)
#pragma unroll
        for (int cf = 0; cf < 4; ++cf)
          acc[p][rf][cf] = __builtin_amdgcn_mfma_f32_16x16x32_f16(a1f[rf][ks], b[cf],
                                                                  acc[p][rf][cf], 0, 0, 0);
    }

    // previous iter's epilogue VALU overlaps pass0's MFMA drain
    if (it > 0) epilogue(acc[p ^ 1], (it - 1) * 64);

    __syncthreads();  // [M] Bs2(it) consumed; drains Bs1(it) staging
    if (it < 15) {    // prefetch Bs2(it+1); drains at [E]
#pragma unroll
      for (int j = 0; j < 4; ++j) {
        const int s = tid + j * 256;
        async_copy16(B2g + (size_t)(c0 + 64) * DDIM + s * 8, Bs2 + s * 8);
      }
    }

    // ---- pass 1: a2 * b1 (fill b1h register cache) ----
    half8 b1h[4][4];
#pragma unroll
    for (int ks = 0; ks < 4; ++ks) {
#pragma unroll
      for (int cf = 0; cf < 4; ++cf)
        b1h[ks][cf] =
            *(const half8*)&Bs1[(cf * 16 + l15) * 128 + (((ks * 4 + q) ^ l15) * 8)];
#pragma unroll
      for (int rf = 0; rf < 2; ++rf)
#pragma unroll
        for (int cf = 0; cf < 4; ++cf)
          acc[p][rf][cf] = __builtin_amdgcn_mfma_f32_16x16x32_f16(a2f[rf][ks], b1h[ks][cf],
                                                                  acc[p][rf][cf], 0, 0, 0);
    }
    // exact pow-2 descale of the two scaled lo-limb passes
#pragma unroll
    for (int rf = 0; rf < 2; ++rf)
#pragma unroll
      for (int cf = 0; cf < 4; ++cf) acc[p][rf][cf] = acc[p][rf][cf] * 4.8828125e-4f;

    // ---- pass 2: a1 * b1 (reuse b1h — same values, zero LDS reads) ----
#pragma unroll
    for (int ks = 0; ks < 4; ++ks) {
#pragma unroll
      for (int rf = 0; rf < 2; ++rf)
#pragma unroll
        for (int cf = 0; cf < 4; ++cf)
          acc[p][rf][cf] = __builtin_amdgcn_mfma_f32_16x16x32_f16(a1f[rf][ks], b1h[ks][cf],
                                                                  acc[p][rf][cf], 0, 0, 0);
    }

    __syncthreads();  // [E] Bs1(it) consumed; drains Bs2(it+1) staging
    if (it < 15) {    // prefetch Bs1(it+1); drains at next [M]
#pragma unroll
      for (int j = 0; j < 4; ++j) {
        const int s = tid + j * 256;
        async_copy16(B1g + (size_t)(c0 + 64) * DDIM + s * 8, Bs1 + s * 8);
      }
    }
  }

  epilogue(acc[1], 960);  // iter 15 (parity 1)

  // cross-lane argmin over the 16 lanes (same q-group) holding different cols
#pragma unroll
  for (int slot = 0; slot < 8; ++slot) {
    float v = mv[slot];
    int i = mi[slot];
#pragma unroll
    for (int m = 1; m <= 8; m <<= 1) {
      float ov = __shfl_xor(v, m);
      int oi = __shfl_xor(i, m);
      if (ov < v || (ov == v && oi < i)) { v = ov; i = oi; }
    }
    mv[slot] = v; mi[slot] = i;
  }

  // waves own disjoint rows -> direct packed store, no cross-wave merge
  if (l15 == 0) {
#pragma unroll
    for (int rf = 0; rf < 2; ++rf) {
      int4v r = {mi[rf * 4 + 0], mi[rf * 4 + 1], mi[rf * 4 + 2], mi[rf * 4 + 3]};
      *(int4v*)&out[row0 + wr * 32 + rf * 16 + q * 4] = r;
    }
  }
}

// ---------------- fallback (ws too small): fp64 dots + np fp32 formula ----------------
__global__ __launch_bounds__(256) void vq_fallback(const float* __restrict__ z,
                                                   const float* __restrict__ cb,
                                                   int* __restrict__ out) {
  __shared__ float zs[DDIM];
  __shared__ float z2s;
  __shared__ float bv[256];
  __shared__ int bi[256];
  const int p = blockIdx.x, tid = threadIdx.x;
  if (tid < DDIM) zs[tid] = z[(size_t)p * DDIM + tid];
  __syncthreads();
  if (tid == 0) z2s = np_sumsq_128(zs);
  __syncthreads();
  const float z2p = z2s;
  float best = 3.0e38f;
  int bidx = 0;
  for (int c = tid; c < KCODES; c += 256) {
    const float* cr = cb + (size_t)c * DDIM;
    double acc = 0.0;
#pragma unroll 8
    for (int d = 0; d < DDIM; ++d) acc += (double)zs[d] * (double)cr[d];
    float dfl = (float)acc;
    float c2k = np_sumsq_128(cr);
    float v = __fadd_rn(__fsub_rn(z2p, __fmul_rn(2.f, dfl)), c2k);
    if (v < best) { best = v; bidx = c; }
  }
  bv[tid] = best; bi[tid] = bidx;
  __syncthreads();
  for (int off = 128; off > 0; off >>= 1) {
    if (tid < off) {
      if (bv[tid + off] < bv[tid] || (bv[tid + off] == bv[tid] && bi[tid + off] < bi[tid])) {
        bv[tid] = bv[tid + off]; bi[tid] = bi[tid + off];
      }
    }
    __syncthreads();
  }
  if (tid == 0) out[p] = bi[0];
}

// ---------------- launcher ----------------
extern "C" void kernel_launch(void* const* d_in, const int* in_sizes, int n_in,
                              void* d_out, int out_size, void* d_ws, size_t ws_size,
                              hipStream_t stream) {
  (void)in_sizes; (void)n_in; (void)out_size;
  const float* z = (const float*)d_in[0];
  const float* cb = (const float*)d_in[1];
  int* out = (int*)d_out;

  if (d_ws != nullptr && ws_size >= WS_NEED) {
    char* ws = (char*)d_ws;
    _Float16* B1 = (_Float16*)(ws + OFF_B1);
    _Float16* B2 = (_Float16*)(ws + OFF_B2);
    float* c2 = (float*)(ws + OFF_C2);

    vq_prep_cb<<<KCODES / 4, 256, 0, stream>>>(cb, B1, B2, c2);
    vq_gemm<<<NPTS / 128, 256, 0, stream>>>(
        z, (const unsigned short*)(ws + OFF_B1), (const unsigned short*)(ws + OFF_B2),
        c2, out);
  } else {
    vq_fallback<<<NPTS, 256, 0, stream>>>(z, cb, out);
  }
}

// Round 7
// 120.390 us; speedup vs baseline: 1.0589x; 1.0589x over previous
//
#include <hip/hip_runtime.h>
#include <stdint.h>

#define NPTS   65536
#define DDIM   128
#define KCODES 1024

typedef __attribute__((ext_vector_type(8))) _Float16  half8;
typedef __attribute__((ext_vector_type(4))) float     f32x4;
typedef __attribute__((ext_vector_type(4))) int       int4v;
typedef __attribute__((ext_vector_type(2))) _Float16  half2v;

// ---------------- numeric helpers (LOCKED — absmax=0 rounds 2..6) ----------------
// 2-limb fp16 Dekker split: x ~= (float)hi + (float)lo / 2048.
__device__ __forceinline__ void split16(float x, _Float16& hi, _Float16& lo) {
  _Float16 h = (__builtin_fabsf(x) < 6.103515625e-05f) ? (_Float16)0.f : (_Float16)x;
  hi = h;
  lo = (_Float16)(__fmul_rn(__fsub_rn(x, (float)h), 2048.f));
}

// numpy pairwise sum of squares for n=128 (bit-exact np.sum(x*x,-1)); serial form.
__device__ __forceinline__ float np_sumsq_128(const float* __restrict__ row) {
  float r[8];
#pragma unroll
  for (int k = 0; k < 8; ++k) r[k] = __fmul_rn(row[k], row[k]);
  for (int i = 8; i < 128; i += 8)
#pragma unroll
    for (int k = 0; k < 8; ++k) r[k] = __fadd_rn(r[k], __fmul_rn(row[i + k], row[i + k]));
  float s01 = __fadd_rn(r[0], r[1]), s23 = __fadd_rn(r[2], r[3]);
  float s45 = __fadd_rn(r[4], r[5]), s67 = __fadd_rn(r[6], r[7]);
  return __fadd_rn(__fadd_rn(s01, s23), __fadd_rn(s45, s67));
}

// global->LDS async copy, 16B/lane. LDS dest = wave-uniform base + lane*16.
__device__ __forceinline__ void async_copy16(const void* g, void* l) {
  auto gp = (const __attribute__((address_space(1))) unsigned int*)(uintptr_t)g;
  auto lp = (__attribute__((address_space(3))) unsigned int*)(unsigned)(uintptr_t)l;
  __builtin_amdgcn_global_load_lds(gp, lp, 16, 0, 0);
}

// ---------------- workspace layout ----------------
constexpr size_t SZ_B   = (size_t)KCODES * DDIM * 2;  // 256 KB per B limb
constexpr size_t OFF_B1 = 0;
constexpr size_t OFF_B2 = SZ_B;
constexpr size_t OFF_C2 = 2 * SZ_B;
constexpr size_t WS_NEED = OFF_C2 + (size_t)KCODES * 4;  // ~516 KB

// ---------------- prep: codebook limbs (XOR-swizzled k-groups) + c2 ----------------
// Element (code,k), kg=k/8, stored at row offset (kg ^ (code&15))*8 + k%8 so that
// linear LDS staging + ds_read_b128 fragment reads are bank-uniform (0 conflicts,
// verified rounds 3-6). c2 via the 8-lane shuffle tree (bit-exact, verified).
__global__ __launch_bounds__(256) void vq_prep_cb(const float* __restrict__ cb,
                                                  _Float16* __restrict__ B1,
                                                  _Float16* __restrict__ B2,
                                                  float* __restrict__ c2) {
  const int w = threadIdx.x >> 6, ln = threadIdx.x & 63;
  const int code = blockIdx.x * 4 + w;  // one wave per code row
  const float2 cv = ((const float2*)(cb + (size_t)code * DDIM))[ln];
  _Float16 h0, l0, h1, l1;
  split16(cv.x, h0, l0); split16(cv.y, h1, l1);
  const int kg = ln >> 2;
  const int o  = 2 * (ln & 3);
  const size_t dst = (size_t)code * DDIM + (size_t)((kg ^ (code & 15)) * 8 + o);
  *(half2v*)(B1 + dst) = (half2v){h0, h1};
  *(half2v*)(B2 + dst) = (half2v){l0, l1};

  if (threadIdx.x < 32) {  // 8 lanes per code, 4 codes
    const int cc = blockIdx.x * 4 + (threadIdx.x >> 3), jj = threadIdx.x & 7;
    const float* row = cb + (size_t)cc * DDIM;
    float e = row[jj];
    float acc = __fmul_rn(e, e);
    for (int i = 1; i < 16; ++i) {
      e = row[i * 8 + jj];
      acc = __fadd_rn(acc, __fmul_rn(e, e));
    }
    float a1 = __fadd_rn(acc, __shfl_xor(acc, 1));
    float a2 = __fadd_rn(a1, __shfl_xor(a1, 2));
    float a4 = __fadd_rn(a2, __shfl_xor(a2, 4));
    if (jj == 0) c2[cc] = a4;
  }
}

// ---------------- main fused z2 + GEMM + argmin ----------------
// grid 512, block 256 = 4 waves stacked by rows: wave tile 32 rows x 64 codes.
// Round-7 = round-5 structure (single acc, immediate epilogue — r6's deferred
// epilogue + double acc spilled: WRITE_SIZE 2.8MB) + ONE change: b1 fragments
// cached in regs across pass1->pass2 (LDS reads 48->32/iter; LDS pipe 74k->49k
// cyc/CU, below the 60k cyc/SIMD MFMA pipe). Register budget ~205-220 < 256.
// Accumulation order per element bit-identical to rounds 2-6.
__global__ __launch_bounds__(256, 2) void vq_gemm(
    const float* __restrict__ z,
    const unsigned short* __restrict__ B1g, const unsigned short* __restrict__ B2g,
    const float* __restrict__ c2g, int* __restrict__ out) {
  __shared__ alignas(16) char smem[33792 + 4096 + 512];  // 38400 B
  unsigned short* Bs1 = (unsigned short*)smem;
  unsigned short* Bs2 = (unsigned short*)(smem + 16384);
  float* c2sh = (float*)(smem + 33792);
  float* z2sh = (float*)(smem + 33792 + 4096);
  float* LsA  = (float*)smem;            // 32x132 fp32, phase 0 only
  float* LsB  = (float*)(smem + 16896);  // second buffer, phase 0 only

  const int tid = threadIdx.x;
  const int ln = tid & 63, wr = tid >> 6;
  const int l15 = ln & 15, q = ln >> 4;
  const size_t row0 = (size_t)blockIdx.x * 128;
  const float4* z4 = (const float4*)z;

  // c2 -> LDS (c2sh disjoint from Ls buffers; drains at any later barrier)
  async_copy16(c2g + tid * 4, c2sh + tid * 4);

  // ---- phase 0: z2 for own 128 rows (np-exact tree; LsA/LsB double-buffer) ----
  auto stagez = [&](int cc, float* Ls) {
#pragma unroll
    for (int j = 0; j < 4; ++j) {
      const int idx = tid + j * 256;  // < 1024 float4 = 32 rows
      float4 v = z4[(row0 + cc * 32) * 32 + idx];
      *(float4*)&Ls[(idx >> 5) * 132 + (idx & 31) * 4] = v;
    }
  };
  stagez(0, LsA);
  for (int cc = 0; cc < 4; ++cc) {
    __syncthreads();
    if (cc < 3) stagez(cc + 1, (cc & 1) ? LsA : LsB);
    const float* Ls = (cc & 1) ? LsB : LsA;
    const int r = tid >> 3, jj = tid & 7;
    const float* row = &Ls[r * 132];
    float e = row[jj];
    float acc = __fmul_rn(e, e);
    for (int i = 1; i < 16; ++i) {
      e = row[i * 8 + jj];
      acc = __fadd_rn(acc, __fmul_rn(e, e));
    }
    float a1 = __fadd_rn(acc, __shfl_xor(acc, 1));
    float a2 = __fadd_rn(a1, __shfl_xor(a1, 2));
    float a4 = __fadd_rn(a2, __shfl_xor(a2, 4));
    if (jj == 0) z2sh[cc * 32 + r] = a4;
  }
  __syncthreads();  // phase-0 reads done; Ls region may now become B tiles

  // ---- stage B tile 0 (both limbs); A-frag loads (L2-warm) overlap the drain ----
#pragma unroll
  for (int j = 0; j < 4; ++j) {
    const int s = tid + j * 256;
    async_copy16(B2g + s * 8, Bs2 + s * 8);
    async_copy16(B1g + s * 8, Bs1 + s * 8);
  }

  half8 a1f[2][4], a2f[2][4];
#pragma unroll
  for (int rf = 0; rf < 2; ++rf) {
    const float* zr = z + (row0 + wr * 32 + rf * 16 + l15) * DDIM;
#pragma unroll
    for (int ks = 0; ks < 4; ++ks) {
      float tmp[8];
      *(float4*)tmp       = *(const float4*)(zr + ks * 32 + q * 8);
      *(float4*)(tmp + 4) = *(const float4*)(zr + ks * 32 + q * 8 + 4);
      half8 h, l;
#pragma unroll
      for (int e = 0; e < 8; ++e) {
        _Float16 hh, ll;
        split16(tmp[e], hh, ll);
        h[e] = hh; l[e] = ll;
      }
      a1f[rf][ks] = h; a2f[rf][ks] = l;
    }
  }

  float mv[8];
  int mi[8];
#pragma unroll
  for (int i = 0; i < 8; ++i) { mv[i] = 3.0e38f; mi[i] = 0; }

  __syncthreads();  // drain B tile 0 + c2 staging

  float z2r[8];
#pragma unroll
  for (int rf = 0; rf < 2; ++rf)
#pragma unroll
    for (int reg = 0; reg < 4; ++reg)
      z2r[rf * 4 + reg] = z2sh[wr * 32 + rf * 16 + q * 4 + reg];

  for (int iter = 0; iter < 16; ++iter) {
    const int c0 = iter * 64;
    f32x4 acc[2][4];
#pragma unroll
    for (int rf = 0; rf < 2; ++rf)
#pragma unroll
      for (int cf = 0; cf < 4; ++cf) acc[rf][cf] = (f32x4){0.f, 0.f, 0.f, 0.f};

    // ---- pass 0: a1 * b2 (reads Bs2 only) ----
#pragma unroll
    for (int ks = 0; ks < 4; ++ks) {
      half8 b[4];
#pragma unroll
      for (int cf = 0; cf < 4; ++cf)
        b[cf] = *(const half8*)&Bs2[(cf * 16 + l15) * 128 + (((ks * 4 + q) ^ l15) * 8)];
#pragma unroll
      for (int rf = 0; rf < 2; ++rf)
#pragma unroll
        for (int cf = 0; cf < 4; ++cf)
          acc[rf][cf] = __builtin_amdgcn_mfma_f32_16x16x32_f16(a1f[rf][ks], b[cf],
                                                               acc[rf][cf], 0, 0, 0);
    }

    __syncthreads();  // [M] Bs2(iter) consumed; drains Bs1(iter) staging
    if (iter < 15) {  // prefetch Bs2(iter+1); drains at [E]
#pragma unroll
      for (int j = 0; j < 4; ++j) {
        const int s = tid + j * 256;
        async_copy16(B2g + (size_t)(c0 + 64) * DDIM + s * 8, Bs2 + s * 8);
      }
    }

    // ---- pass 1: a2 * b1 (fill b1h register cache) ----
    half8 b1h[4][4];
#pragma unroll
    for (int ks = 0; ks < 4; ++ks) {
#pragma unroll
      for (int cf = 0; cf < 4; ++cf)
        b1h[ks][cf] =
            *(const half8*)&Bs1[(cf * 16 + l15) * 128 + (((ks * 4 + q) ^ l15) * 8)];
#pragma unroll
      for (int rf = 0; rf < 2; ++rf)
#pragma unroll
        for (int cf = 0; cf < 4; ++cf)
          acc[rf][cf] = __builtin_amdgcn_mfma_f32_16x16x32_f16(a2f[rf][ks], b1h[ks][cf],
                                                               acc[rf][cf], 0, 0, 0);
    }
    // exact pow-2 descale of the two scaled lo-limb passes
#pragma unroll
    for (int rf = 0; rf < 2; ++rf)
#pragma unroll
      for (int cf = 0; cf < 4; ++cf) acc[rf][cf] = acc[rf][cf] * 4.8828125e-4f;

    // ---- pass 2: a1 * b1 (reuse b1h — same values, zero LDS reads) ----
#pragma unroll
    for (int ks = 0; ks < 4; ++ks) {
#pragma unroll
      for (int rf = 0; rf < 2; ++rf)
#pragma unroll
        for (int cf = 0; cf < 4; ++cf)
          acc[rf][cf] = __builtin_amdgcn_mfma_f32_16x16x32_f16(a1f[rf][ks], b1h[ks][cf],
                                                               acc[rf][cf], 0, 0, 0);
    }

    // ---- epilogue: np-exact fp32 distance, fold into running argmin ----
    // fma(-2,dot,z2) == fsub(z2, fmul(2,dot)) bit-exactly (2*dot exact, one rounding)
#pragma unroll
    for (int rf = 0; rf < 2; ++rf)
#pragma unroll
      for (int reg = 0; reg < 4; ++reg) {
        const int slot = rf * 4 + reg;
#pragma unroll
        for (int cf = 0; cf < 4; ++cf) {
          const float c2v = c2sh[c0 + cf * 16 + l15];
          float v = __fadd_rn(__builtin_fmaf(-2.f, acc[rf][cf][reg], z2r[slot]), c2v);
          int idx = c0 + cf * 16 + l15;
          if (v < mv[slot]) { mv[slot] = v; mi[slot] = idx; }
        }
      }

    __syncthreads();  // [E] Bs1(iter) consumed; drains Bs2(iter+1) staging
    if (iter < 15) {  // prefetch Bs1(iter+1); drains at next [M]
#pragma unroll
      for (int j = 0; j < 4; ++j) {
        const int s = tid + j * 256;
        async_copy16(B1g + (size_t)(c0 + 64) * DDIM + s * 8, Bs1 + s * 8);
      }
    }
  }

  // cross-lane argmin over the 16 lanes (same q-group) holding different cols
#pragma unroll
  for (int slot = 0; slot < 8; ++slot) {
    float v = mv[slot];
    int i = mi[slot];
#pragma unroll
    for (int m = 1; m <= 8; m <<= 1) {
      float ov = __shfl_xor(v, m);
      int oi = __shfl_xor(i, m);
      if (ov < v || (ov == v && oi < i)) { v = ov; i = oi; }
    }
    mv[slot] = v; mi[slot] = i;
  }

  // waves own disjoint rows -> direct packed store, no cross-wave merge
  if (l15 == 0) {
#pragma unroll
    for (int rf = 0; rf < 2; ++rf) {
      int4v r = {mi[rf * 4 + 0], mi[rf * 4 + 1], mi[rf * 4 + 2], mi[rf * 4 + 3]};
      *(int4v*)&out[row0 + wr * 32 + rf * 16 + q * 4] = r;
    }
  }
}

// ---------------- fallback (ws too small): fp64 dots + np fp32 formula ----------------
__global__ __launch_bounds__(256) void vq_fallback(const float* __restrict__ z,
                                                   const float* __restrict__ cb,
                                                   int* __restrict__ out) {
  __shared__ float zs[DDIM];
  __shared__ float z2s;
  __shared__ float bv[256];
  __shared__ int bi[256];
  const int p = blockIdx.x, tid = threadIdx.x;
  if (tid < DDIM) zs[tid] = z[(size_t)p * DDIM + tid];
  __syncthreads();
  if (tid == 0) z2s = np_sumsq_128(zs);
  __syncthreads();
  const float z2p = z2s;
  float best = 3.0e38f;
  int bidx = 0;
  for (int c = tid; c < KCODES; c += 256) {
    const float* cr = cb + (size_t)c * DDIM;
    double acc = 0.0;
#pragma unroll 8
    for (int d = 0; d < DDIM; ++d) acc += (double)zs[d] * (double)cr[d];
    float dfl = (float)acc;
    float c2k = np_sumsq_128(cr);
    float v = __fadd_rn(__fsub_rn(z2p, __fmul_rn(2.f, dfl)), c2k);
    if (v < best) { best = v; bidx = c; }
  }
  bv[tid] = best; bi[tid] = bidx;
  __syncthreads();
  for (int off = 128; off > 0; off >>= 1) {
    if (tid < off) {
      if (bv[tid + off] < bv[tid] || (bv[tid + off] == bv[tid] && bi[tid + off] < bi[tid])) {
        bv[tid] = bv[tid + off]; bi[tid] = bi[tid + off];
      }
    }
    __syncthreads();
  }
  if (tid == 0) out[p] = bi[0];
}

// ---------------- launcher ----------------
extern "C" void kernel_launch(void* const* d_in, const int* in_sizes, int n_in,
                              void* d_out, int out_size, void* d_ws, size_t ws_size,
                              hipStream_t stream) {
  (void)in_sizes; (void)n_in; (void)out_size;
  const float* z = (const float*)d_in[0];
  const float* cb = (const float*)d_in[1];
  int* out = (int*)d_out;

  if (d_ws != nullptr && ws_size >= WS_NEED) {
    char* ws = (char*)d_ws;
    _Float16* B1 = (_Float16*)(ws + OFF_B1);
    _Float16* B2 = (_Float16*)(ws + OFF_B2);
    float* c2 = (float*)(ws + OFF_C2);

    vq_prep_cb<<<KCODES / 4, 256, 0, stream>>>(cb, B1, B2, c2);
    vq_gemm<<<NPTS / 128, 256, 0, stream>>>(
        z, (const unsigned short*)(ws + OFF_B1), (const unsigned short*)(ws + OFF_B2),
        c2, out);
  } else {
    vq_fallback<<<NPTS, 256, 0, stream>>>(z, cb, out);
  }
}